// Round 1
// baseline (365.026 us; speedup 1.0000x reference)
//
#include <hip/hip_runtime.h>

// Problem constants (from reference setup_inputs)
#define BATCHES 64
#define PATCHES 4096
#define PATCH_ELEMS 256          // 16*16
#define NBINS 257                // patch_size^2 + 1
#define BLOCKS_PER_BATCH 16
#define PATCHES_PER_BLOCK (PATCHES / BLOCKS_PER_BATCH)  // 256

// One wave (64 lanes) reduces one patch: lane i loads float4 at patch+4i
// -> perfectly coalesced 1 KiB per wave-load. Shuffle-reduce to lane 0,
// LDS int histogram per block, float-atomic flush (exact: all multiples of 2^-12).
__global__ __launch_bounds__(256)
void Probability_66048007078103_kernel(const float* __restrict__ in,
                                       float* __restrict__ out) {
    __shared__ int hist[NBINS];
    for (int i = threadIdx.x; i < NBINS; i += 256) hist[i] = 0;
    __syncthreads();

    const int batch = blockIdx.x & (BATCHES - 1);   // consecutive blocks -> different batches (XCD spread)
    const int slice = blockIdx.x >> 6;              // / BATCHES
    const int lane  = threadIdx.x & 63;
    const int wave  = threadIdx.x >> 6;             // 0..3

    const int p_start = slice * PATCHES_PER_BLOCK;
    const float4* in4 = (const float4*)(in + (size_t)batch * PATCHES * PATCH_ELEMS);

    // ILP-2: each wave handles patches (p, p+4) per iteration, stride 8.
    for (int p = p_start + wave; p < p_start + PATCHES_PER_BLOCK; p += 8) {
        float4 v0 = in4[(size_t)p * 64 + lane];
        float4 v1 = in4[(size_t)(p + 4) * 64 + lane];
        float s0 = (v0.x + v0.y) + (v0.z + v0.w);
        float s1 = (v1.x + v1.y) + (v1.z + v1.w);
        #pragma unroll
        for (int off = 32; off > 0; off >>= 1) {
            s0 += __shfl_down(s0, off, 64);
            s1 += __shfl_down(s1, off, 64);
        }
        if (lane == 0) {
            atomicAdd(&hist[(int)(s0 + 0.5f)], 1);
            atomicAdd(&hist[(int)(s1 + 0.5f)], 1);
        }
    }
    __syncthreads();

    const float invP = 1.0f / (float)PATCHES;
    for (int i = threadIdx.x; i < NBINS; i += 256) {
        int c = hist[i];
        if (c) atomicAdd(&out[batch * NBINS + i], (float)c * invP);
    }
}

extern "C" void kernel_launch(void* const* d_in, const int* in_sizes, int n_in,
                              void* d_out, int out_size, void* d_ws, size_t ws_size,
                              hipStream_t stream) {
    const float* in = (const float*)d_in[0];
    float* out = (float*)d_out;
    // d_out is poisoned to 0xAA before every timed launch — zero it (memset node is graph-capturable).
    hipMemsetAsync(out, 0, (size_t)out_size * sizeof(float), stream);
    Probability_66048007078103_kernel<<<BATCHES * BLOCKS_PER_BATCH, 256, 0, stream>>>(in, out);
}

// Round 2
// 352.743 us; speedup vs baseline: 1.0348x; 1.0348x over previous
//
#include <hip/hip_runtime.h>

// Problem constants (from reference setup_inputs)
#define BATCHES 64
#define PATCHES 4096
#define PATCH_ELEMS 256          // 16*16
#define NBINS 257                // patch_size^2 + 1
#define BLOCKS_PER_BATCH 32
#define PATCHES_PER_BLOCK (PATCHES / BLOCKS_PER_BATCH)  // 128

// v2: 16 lanes per patch. Each lane sums 16 contiguous elements (4x float4,
// all loads independent and issued up-front), then a 4-level width-16 shuffle
// reduce yields 4 patch sums per wave-group. 8 patches (2 groups) per
// iteration -> 8 dwordx4 loads in flight per lane. vs v1: shuffle chain 4 deep
// (was 6), 1 shuffle-instr/patch (was 6), 2x grid for latency hiding.
__global__ __launch_bounds__(256)
void Probability_66048007078103_kernel(const float* __restrict__ in,
                                       float* __restrict__ out) {
    __shared__ int hist[NBINS];
    for (int i = threadIdx.x; i < NBINS; i += 256) hist[i] = 0;
    __syncthreads();

    const int batch = blockIdx.x & (BATCHES - 1);   // consecutive blocks -> different batches (XCD spread)
    const int slice = blockIdx.x >> 6;              // 0..31
    const int lane  = threadIdx.x & 63;
    const int wave  = threadIdx.x >> 6;             // 0..3
    const int sub   = lane >> 4;                    // patch-within-group 0..3
    const int t     = lane & 15;                    // 16 lanes per patch

    const float4* in4 = (const float4*)(in + (size_t)batch * PATCHES * PATCH_ELEMS);
    const int p_start = slice * PATCHES_PER_BLOCK;  // 128 patches per block

    // Each wave handles 32 patches: 4 iterations x 8 patches (2 groups of 4).
    for (int i = 0; i < 4; ++i) {
        const int pA = p_start + i * 32 + wave * 8 + sub;       // group A patch
        const int pB = pA + 4;                                  // group B patch
        const float4* a = &in4[(size_t)pA * 64 + t * 4];
        const float4* b = &in4[(size_t)pB * 64 + t * 4];
        // 8 independent 16B loads in flight
        float4 a0 = a[0], a1 = a[1], a2 = a[2], a3 = a[3];
        float4 b0 = b[0], b1 = b[1], b2 = b[2], b3 = b[3];
        float sA = ((a0.x + a0.y) + (a0.z + a0.w)) + ((a1.x + a1.y) + (a1.z + a1.w))
                 + ((a2.x + a2.y) + (a2.z + a2.w)) + ((a3.x + a3.y) + (a3.z + a3.w));
        float sB = ((b0.x + b0.y) + (b0.z + b0.w)) + ((b1.x + b1.y) + (b1.z + b1.w))
                 + ((b2.x + b2.y) + (b2.z + b2.w)) + ((b3.x + b3.y) + (b3.z + b3.w));
        // reduce across the 16 lanes of each patch (two chains interleave)
        #pragma unroll
        for (int off = 8; off > 0; off >>= 1) {
            sA += __shfl_down(sA, off, 16);
            sB += __shfl_down(sB, off, 16);
        }
        if (t == 0) {
            atomicAdd(&hist[(int)(sA + 0.5f)], 1);
            atomicAdd(&hist[(int)(sB + 0.5f)], 1);
        }
    }
    __syncthreads();

    const float invP = 1.0f / (float)PATCHES;
    for (int i = threadIdx.x; i < NBINS; i += 256) {
        int c = hist[i];
        if (c) atomicAdd(&out[batch * NBINS + i], (float)c * invP);
    }
}

extern "C" void kernel_launch(void* const* d_in, const int* in_sizes, int n_in,
                              void* d_out, int out_size, void* d_ws, size_t ws_size,
                              hipStream_t stream) {
    const float* in = (const float*)d_in[0];
    float* out = (float*)d_out;
    // d_out is poisoned to 0xAA before every timed launch — zero it (memset node is graph-capturable).
    hipMemsetAsync(out, 0, (size_t)out_size * sizeof(float), stream);
    Probability_66048007078103_kernel<<<BATCHES * BLOCKS_PER_BATCH, 256, 0, stream>>>(in, out);
}